// Round 6
// baseline (288.585 us; speedup 1.0000x reference)
//
#include <hip/hip_runtime.h>
#include <math.h>

// SGRUCell T=32 B=8 I=512 H=512, all f32.
// Persistent kernel: block (q=blk>>3, b=blk&7) owns rows i in [16q,16q+16) of
// batch b; 16 waves, one row per wave.
//
// Exchange (R4, validated champion): producer waves gather hn into LDS; after
// the gather barrier wave 15 issues ONE 16-lane contiguous 64B store of
// SIGN-TAGGED values (hn>=0 => sign bit free) to a write-once workspace line.
// Consumer: wave 0 ONLY polls 32 tag words (narrow), barrier, 512-wide
// one-shot read with per-word tag verify (~never loops).
// Hard-won invariants (R1/R2/R5 regressions, all with WRITE_SIZE growth as
// the fingerprint): (1) polled lines quiesce (one dirty transition per step);
// (2) no RMW flag lines; (3) EXACTLY ONE spinning wave per block (R5: 16
// spinning waves => +11MB WRITE, +54us); (4) never wide-poll in-flight data.
//
// R6 delta vs R4 (the isolated, fabric-neutral half of R5): te ping-pong fold.
// sh_te[2][512]; every wave recomputes te_new[j] = fmaf(taue, hprev[j]-te[j],
// te[j]) inside the fused tE/D loop (bitwise-identical expression to R4's te
// pass => cross-block determinism preserved); thread tid (waves 0-7, m==w)
// writes element tid to the other slot. Deletes the 512-wide te pass + one
// barrier: 5 -> 4 barriers/step.
// Races: sh_te slot read at t rewritten at fused(t+1) -- b4(t), b1(t+1),
// b2(t+1) intervene. sh_hbuf slot written fill(t), last read fused(t+1),
// rewritten fill(t+2) -- b4(t+1) intervenes. sh_gates written (b2..b3)(t),
// read fused(t), rewritten (t+1) after b2(t+1). sh_gather written fused(t),
// read post-b4(t) by wave15, rewritten fused(t+1) after b3(t+1).

#define ATOMIC_LD(p) __hip_atomic_load((p), __ATOMIC_RELAXED, __HIP_MEMORY_SCOPE_AGENT)
#define ATOMIC_ST(p, v) __hip_atomic_store((p), (v), __ATOMIC_RELAXED, __HIP_MEMORY_SCOPE_AGENT)

__device__ __forceinline__ float wred(float v) {
#pragma unroll
  for (int o = 32; o > 0; o >>= 1) v += __shfl_xor(v, o, 64);
  return v;
}
__device__ __forceinline__ float sigm(float x) { return 1.f / (1.f + __expf(-x)); }

__global__ void prenorm_kernel(const float* __restrict__ xv, const float* __restrict__ xg,
                               const float* __restrict__ hv, const float* __restrict__ hg,
                               float* __restrict__ scx, float* __restrict__ sch,
                               unsigned* __restrict__ exch) {
  int r = blockIdx.x, L = threadIdx.x;
  // exch is poisoned 0xAA (sign bit SET = would look ready): clear 131072 words.
  if (r < 2048) exch[r * 64 + L] = 0u;
  const float* vrow; const float* g; float* o; int rr;
  if (r < 1536) { rr = r; vrow = xv + (size_t)r * 512; g = xg; o = scx; }
  else { rr = r - 1536; vrow = hv + (size_t)rr * 512; g = hg; o = sch; }
  float s = 0.f;
#pragma unroll
  for (int m = 0; m < 8; m++) { float v = vrow[m * 64 + L]; s = fmaf(v, v, s); }
  s = wred(s);
  if (L == 0) o[rr] = g[rr] / sqrtf(s);
}

__global__ __launch_bounds__(1024, 4) void persist_kernel(
    const float* __restrict__ x,
    const float* __restrict__ h0, const float* __restrict__ v0,
    const float* __restrict__ dU0, const float* __restrict__ te0,
    const float* __restrict__ tE0,
    const float* __restrict__ x2h_v, const float* __restrict__ x2h_b,
    const float* __restrict__ h2h_v, const float* __restrict__ h2h_b,
    const float* __restrict__ alpha,
    const float* __restrict__ h2mod_w, const float* __restrict__ h2mod_b,
    const float* __restrict__ modU_w, const float* __restrict__ modU_b,
    const float* __restrict__ scx, const float* __restrict__ sch,
    unsigned* __restrict__ exch,
    float* __restrict__ o_v, float* __restrict__ o_h,
    float* __restrict__ o_dU, float* __restrict__ o_te,
    float* __restrict__ o_tE, float* __restrict__ o_outs) {
  __shared__ float sh_hbuf[2][512];   // h ping-pong: buf[t&1] = h_t
  __shared__ float sh_te[2][512];     // eligibility trace ping-pong
  __shared__ float sh_mod[2048];      // h2mod_w (4x512)
  __shared__ float sh_xpz[32][16];    // precomputed x-proj (z) + bias, [t][w]
  __shared__ float sh_xpdv[32][16];   // precomputed x-proj (dv) + bias
  __shared__ float sh_gates[4];       // tau_e, tau_E, tau_U, mU
  __shared__ float sh_gather[16];     // per-wave hn gather for the 64B store

  const int tid = threadIdx.x;
  const int w = tid >> 6, L = tid & 63;
  const int b = blockIdx.x & 7, q = blockIdx.x >> 3;
  const int i = q * 16 + w;  // owned row

  // ---- basic LDS staging ----
  if (tid < 512) {
    sh_hbuf[0][tid] = h0[b * 512 + tid];
    sh_te[0][tid] = te0[b * 512 + tid];
  }
  sh_mod[tid] = h2mod_w[tid];
  sh_mod[tid + 1024] = h2mod_w[tid + 1024];

  const int rz = i, rdv = 1024 + i, rr = 512 + i;
  const size_t row  = ((size_t)(b * 512 + i)) * 512;
  const size_t wrow = (size_t)i * 512;

  // ---- x-projection precompute FIRST (keeps register pressure low) ----
  {
    float xz[8], xdv[8];
    const float sx_z = scx[rz], sx_dv = scx[rdv];
#pragma unroll
    for (int m = 0; m < 8; m++) {
      int c = m * 64 + L;
      xz[m]  = sx_z  * x2h_v[(size_t)rz  * 512 + c];
      xdv[m] = sx_dv * x2h_v[(size_t)rdv * 512 + c];
    }
    float bz = 0.f, bdv = 0.f;
    if (L == 0) {
      bz  = x2h_b[i] + h2h_b[i];
      bdv = x2h_b[1024 + i] + h2h_b[1024 + i];
    }
#pragma unroll 4
    for (int t = 0; t < 32; t++) {
      const float* xr = x + (size_t)t * 4096 + b * 512;
      float a = 0.f, d = 0.f;
#pragma unroll
      for (int m = 0; m < 8; m++) {
        int c = m * 64 + L;
        float xv_ = xr[c];
        a = fmaf(xz[m], xv_, a);
        d = fmaf(xdv[m], xv_, d);
      }
      a = wred(a); d = wred(d);
      if (L == 0) { sh_xpz[t][w] = a + bz; sh_xpdv[t][w] = d + bdv; }
    }
  }

  // ---- persistent register tables (9x8 = 72 floats, as R4) ----
  float wz[8], wdv[8], mw[8], mb[8], al[8], upS[8], loS[8], D[8], tE[8];
  {
    const float s_z = sch[rz], s_dv = sch[rdv], s_r = sch[rr];
#pragma unroll
    for (int m = 0; m < 8; m++) {
      int c = m * 64 + L;
      wz[m]  = s_z  * h2h_v[(size_t)rz  * 512 + c];
      wdv[m] = s_dv * h2h_v[(size_t)rdv * 512 + c];
      mw[m] = modU_w[wrow + c];
      mb[m] = modU_b[wrow + c];
      float alv = alpha[wrow + c];
      al[m] = alv;
      float wrv = s_r * h2h_v[(size_t)rr * 512 + c];
      float t1 = alv / (alv + 1e-5f);   // alpha * (1/(alpha+eps)), prescaled
      upS[m] = fmaxf(1.f - wrv, 0.f) * t1;
      loS[m] = -fmaxf(1.f + wrv, 0.f) * t1;
      float dui = dU0[row + c];
      D[m]  = alv * dui;                // scaled state: D = alpha * dU
      tE[m] = tE0[row + c];
    }
  }
  float v_reg = 0.f, hn_last = 0.f, gb = 0.f;
  if (L == 0) {
    v_reg = v0[b * 512 + i];
    if (w < 4) gb = h2mod_b[w];
  }
  __syncthreads();

  for (int t = 0; t <= 32; t++) {
    const int cur = t & 1, prev = cur ^ 1;
    if (t > 0) {
      const unsigned* eb = exch + ((t - 1) * 8 + b) * 512;
      // ---- arrival: wave 0 polls 32 tag words (one per producer line) ----
      if (w == 0) {
        const unsigned* fp = eb + (L & 31) * 16 + (L & 15);
        unsigned u;
        do {
          u = ATOMIC_LD(fp);
        } while (!__all(u >> 31));
      }
      __syncthreads();  // b1
      if (tid < 512) {  // one-shot read of h_t, per-word tag verify (~never loops)
        unsigned u = ATOMIC_LD(eb + tid);
        while (!(u >> 31)) u = ATOMIC_LD(eb + tid);
        sh_hbuf[cur][tid] = __uint_as_float(u & 0x7fffffffu);
      }
      __syncthreads();  // b2: sh_hbuf[cur] = h_t complete
      // gates: mod = h_t @ h2mod_w.T + b, waves 0..3
      if (w < 4) {
        float p = 0.f;
        const float* mr = sh_mod + w * 512;
#pragma unroll
        for (int m = 0; m < 8; m++) {
          int c = m * 64 + L;
          p = fmaf(sh_hbuf[cur][c], mr[c], p);
        }
        p = wred(p);
        if (L == 0) {
          p += gb;
          sh_gates[w] = (w == 3) ? fmaxf(p, 0.f) : sigm(p);
        }
      }
      __syncthreads();  // b3: gates ready
      // fused: te-fold (replaces R4's te pass + barrier) + tE/D update
      float taue = sh_gates[0];
      float tauE = sh_gates[1], tauU = sh_gates[2], mU = sh_gates[3];
      float hn_i = sh_hbuf[cur][i];
      float te_i = sh_te[prev][i];
      te_i = fmaf(taue, sh_hbuf[prev][i] - te_i, te_i);
#pragma unroll
      for (int m = 0; m < 8; m++) {
        int j = m * 64 + L;
        float tej = sh_te[prev][j];
        float te_new = fmaf(taue, sh_hbuf[prev][j] - tej, tej);
        if (m == w) sh_te[cur][j] = te_new;   // thread tid owns element tid
        float outer = hn_i * te_new - te_i * sh_hbuf[cur][j];
        float tEn = tE[m] + tauE * (outer - tE[m]);
        float a = fmaf(mU, mw[m], mb[m]);
        float sshr = (a > 0.5f) ? (a - 0.5f) : ((a < -0.5f) ? (a + 0.5f) : 0.f);
        float Dn = D[m] + tauU * (sshr * (al[m] * tEn) - D[m]);
        D[m] = fminf(fmaxf(Dn, loS[m]), upS[m]);
        tE[m] = tEn;
      }
    }

    if (t < 32) {
      // z/dv dots for step t (x-part precomputed; D = alpha*dU directly)
      float p1 = 0.f, p2 = 0.f;
#pragma unroll
      for (int m = 0; m < 8; m++) {
        int c = m * 64 + L;
        float hc = sh_hbuf[cur][c];
        p1 = fmaf(wz[m], hc, p1);
        p2 = fmaf(wdv[m] + D[m], hc, p2);
      }
      p1 = wred(p1); p2 = wred(p2);
      if (L == 0) {
        float z = sigm(p1 + sh_xpz[t][w]);
        float dv = p2 + sh_xpdv[t][w];
        v_reg += z * (dv - v_reg);
        hn_last = fmaxf(v_reg, 0.f);
        o_outs[(size_t)t * 4096 + b * 512 + i] = hn_last;  // clean copy, fire&forget
        sh_gather[w] = hn_last;                            // LDS gather for exchange
      }
      __syncthreads();  // b4: orders the gather; only plain stores outstanding
      if (w == 15 && L < 16) {
        // ONE 16-lane contiguous 64B tagged store: data is its own flag.
        unsigned u = __float_as_uint(sh_gather[L]) | 0x80000000u;
        ATOMIC_ST(exch + (t * 8 + b) * 512 + q * 16 + L, u);
      }
    }
  }

  // ---- final writes ----
#pragma unroll
  for (int m = 0; m < 8; m++) {
    int c = m * 64 + L;
    float alv = al[m];
    o_dU[row + c] = (alv != 0.f) ? D[m] * __builtin_amdgcn_rcpf(alv) : 0.f;
    o_tE[row + c] = tE[m];
  }
  if (L == 0) {
    o_v[b * 512 + i] = v_reg;
    o_h[b * 512 + i] = hn_last;
  }
  // te final state: t=32 fused wrote sh_te[0] (cur=0); element tid was written
  // by thread tid itself (m==w path) -> same-thread dep, no barrier needed.
  if (q == 0 && tid < 512) o_te[b * 512 + tid] = sh_te[0][tid];
}

extern "C" void kernel_launch(void* const* d_in, const int* in_sizes, int n_in,
                              void* d_out, int out_size, void* d_ws, size_t ws_size,
                              hipStream_t stream) {
  const float* x       = (const float*)d_in[0];
  const float* h0      = (const float*)d_in[1];
  const float* v0      = (const float*)d_in[2];
  const float* dU0     = (const float*)d_in[3];
  const float* te0     = (const float*)d_in[4];
  const float* tE0     = (const float*)d_in[5];
  const float* x2h_v   = (const float*)d_in[6];
  const float* x2h_g   = (const float*)d_in[7];
  const float* x2h_b   = (const float*)d_in[8];
  const float* h2h_v   = (const float*)d_in[9];
  const float* h2h_g   = (const float*)d_in[10];
  const float* h2h_b   = (const float*)d_in[11];
  const float* alpha   = (const float*)d_in[12];
  const float* h2mod_w = (const float*)d_in[13];
  const float* h2mod_b = (const float*)d_in[14];
  const float* modU_w  = (const float*)d_in[15];
  const float* modU_b  = (const float*)d_in[16];

  float* out = (float*)d_out;
  // output layout: v(4096) h(4096) dU(2097152) te(4096) tE(2097152) outs(131072)
  float* o_v    = out;
  float* o_h    = out + 4096;
  float* o_dU   = out + 8192;
  float* o_te   = out + 2105344;
  float* o_tE   = out + 2109440;
  float* o_outs = out + 4206592;

  float* wsf = (float*)d_ws;
  float* scx = wsf + 8192;                    // 1536 floats
  float* sch = wsf + 9728;                    // 1536 floats
  unsigned* exch = (unsigned*)d_ws + 12288;   // 32*8*32 lines x 16 words = 512KB

  prenorm_kernel<<<dim3(3072), dim3(64), 0, stream>>>(x2h_v, x2h_g, h2h_v, h2h_g,
                                                      scx, sch, exch);

  persist_kernel<<<dim3(256), dim3(1024), 0, stream>>>(
      x, h0, v0, dU0, te0, tE0, x2h_v, x2h_b, h2h_v, h2h_b, alpha,
      h2mod_w, h2mod_b, modU_w, modU_b, scx, sch, exch,
      o_v, o_h, o_dU, o_te, o_tE, o_outs);
}

// Round 7
// 250.303 us; speedup vs baseline: 1.1529x; 1.1529x over previous
//
#include <hip/hip_runtime.h>
#include <math.h>

// SGRUCell T=32 B=8 I=512 H=512, all f32.
// Persistent kernel: block (q=blk>>3, b=blk&7) owns rows i in [16q,16q+16) of
// batch b; 16 waves, one row per wave. Body = R4 champion (143.5us) verbatim.
// R3/R5/R6 lesson: the intra-block structure is at a register-pressure local
// optimum (128 regs/thread hard cap at 16 waves/CU); fused-loop edits spill
// to scratch (WRITE_SIZE +10..17MB fingerprint). Do not touch it.
//
// R7 delta: two-tier exchange latency. b = blockIdx&7 means all 32 blocks of
// a batch share blockIdx%8 -> under round-robin dispatch they share ONE XCD
// and thus ONE physical L2 (a real coherence point at ~200cy vs ~900cy IC).
//   producer (wave15): store tagged 64B line sc0+sc1 (IC, always-correct)
//   then sc0-only (dirties the SHARED XCD L2: fast path, same value).
//   consumer: poll/read with sc0 loads (local L2 hits, ZERO fabric traffic);
//   every-Nth poll iteration and the read-retry path use sc0+sc1 (IC truth)
//   so a wrong XCD-mapping assumption degrades speed, never correctness.
// Invariants kept: narrow poll (wave 0 only), write-once lines, no RMW,
// no wide-polling of in-flight data. Prenorm zero-clears are IC-visible at
// persist start (inter-kernel release writes back L2) -> no stale dirty
// zeros can clobber the exchange lines.

#define ATOMIC_ST(p, v) __hip_atomic_store((p), (v), __ATOMIC_RELAXED, __HIP_MEMORY_SCOPE_AGENT)

// sc0: bypass L1, served by the (shared, same-XCD) L2.
__device__ __forceinline__ unsigned ld_l2(const unsigned* p) {
  unsigned v;
  asm volatile("global_load_dword %0, %1, off sc0\n\ts_waitcnt vmcnt(0)"
               : "=v"(v) : "v"(p) : "memory");
  return v;
}
// sc0+sc1: bypass L1 and L2 -> device coherence point (agent-scope truth).
__device__ __forceinline__ unsigned ld_ic(const unsigned* p) {
  unsigned v;
  asm volatile("global_load_dword %0, %1, off sc0 sc1\n\ts_waitcnt vmcnt(0)"
               : "=v"(v) : "v"(p) : "memory");
  return v;
}
__device__ __forceinline__ void st_l2(unsigned* p, unsigned v) {
  asm volatile("global_store_dword %0, %1, off sc0" :: "v"(p), "v"(v) : "memory");
}
__device__ __forceinline__ void st_ic(unsigned* p, unsigned v) {
  asm volatile("global_store_dword %0, %1, off sc0 sc1" :: "v"(p), "v"(v) : "memory");
}

__device__ __forceinline__ float wred(float v) {
#pragma unroll
  for (int o = 32; o > 0; o >>= 1) v += __shfl_xor(v, o, 64);
  return v;
}
__device__ __forceinline__ float sigm(float x) { return 1.f / (1.f + __expf(-x)); }

__global__ void prenorm_kernel(const float* __restrict__ xv, const float* __restrict__ xg,
                               const float* __restrict__ hv, const float* __restrict__ hg,
                               float* __restrict__ scx, float* __restrict__ sch,
                               unsigned* __restrict__ exch) {
  int r = blockIdx.x, L = threadIdx.x;
  // exch is poisoned 0xAA (sign bit SET = would look ready): clear 131072 words.
  if (r < 2048) exch[r * 64 + L] = 0u;
  const float* vrow; const float* g; float* o; int rr;
  if (r < 1536) { rr = r; vrow = xv + (size_t)r * 512; g = xg; o = scx; }
  else { rr = r - 1536; vrow = hv + (size_t)rr * 512; g = hg; o = sch; }
  float s = 0.f;
#pragma unroll
  for (int m = 0; m < 8; m++) { float v = vrow[m * 64 + L]; s = fmaf(v, v, s); }
  s = wred(s);
  if (L == 0) o[rr] = g[rr] / sqrtf(s);
}

__global__ __launch_bounds__(1024, 4) void persist_kernel(
    const float* __restrict__ x,
    const float* __restrict__ h0, const float* __restrict__ v0,
    const float* __restrict__ dU0, const float* __restrict__ te0,
    const float* __restrict__ tE0,
    const float* __restrict__ x2h_v, const float* __restrict__ x2h_b,
    const float* __restrict__ h2h_v, const float* __restrict__ h2h_b,
    const float* __restrict__ alpha,
    const float* __restrict__ h2mod_w, const float* __restrict__ h2mod_b,
    const float* __restrict__ modU_w, const float* __restrict__ modU_b,
    const float* __restrict__ scx, const float* __restrict__ sch,
    unsigned* __restrict__ exch,
    float* __restrict__ o_v, float* __restrict__ o_h,
    float* __restrict__ o_dU, float* __restrict__ o_te,
    float* __restrict__ o_tE, float* __restrict__ o_outs) {
  __shared__ float sh_hbuf[2][512];   // h ping-pong: buf[t&1] = h_t
  __shared__ float sh_te[512];        // eligibility trace
  __shared__ float sh_mod[2048];      // h2mod_w (4x512)
  __shared__ float sh_xpz[32][16];    // precomputed x-proj (z) + bias, [t][w]
  __shared__ float sh_xpdv[32][16];   // precomputed x-proj (dv) + bias
  __shared__ float sh_gates[4];       // tau_e, tau_E, tau_U, mU
  __shared__ float sh_gather[16];     // per-wave hn gather for the 64B store

  const int tid = threadIdx.x;
  const int w = tid >> 6, L = tid & 63;
  const int b = blockIdx.x & 7, q = blockIdx.x >> 3;
  const int i = q * 16 + w;  // owned row

  // ---- basic LDS staging ----
  if (tid < 512) {
    sh_hbuf[0][tid] = h0[b * 512 + tid];
    sh_te[tid] = te0[b * 512 + tid];
  }
  sh_mod[tid] = h2mod_w[tid];
  sh_mod[tid + 1024] = h2mod_w[tid + 1024];

  const int rz = i, rdv = 1024 + i, rr = 512 + i;
  const size_t row  = ((size_t)(b * 512 + i)) * 512;
  const size_t wrow = (size_t)i * 512;

  // ---- x-projection precompute FIRST (keeps register pressure low) ----
  {
    float xz[8], xdv[8];
    const float sx_z = scx[rz], sx_dv = scx[rdv];
#pragma unroll
    for (int m = 0; m < 8; m++) {
      int c = m * 64 + L;
      xz[m]  = sx_z  * x2h_v[(size_t)rz  * 512 + c];
      xdv[m] = sx_dv * x2h_v[(size_t)rdv * 512 + c];
    }
    float bz = 0.f, bdv = 0.f;
    if (L == 0) {
      bz  = x2h_b[i] + h2h_b[i];
      bdv = x2h_b[1024 + i] + h2h_b[1024 + i];
    }
#pragma unroll 4
    for (int t = 0; t < 32; t++) {
      const float* xr = x + (size_t)t * 4096 + b * 512;
      float a = 0.f, d = 0.f;
#pragma unroll
      for (int m = 0; m < 8; m++) {
        int c = m * 64 + L;
        float xv_ = xr[c];
        a = fmaf(xz[m], xv_, a);
        d = fmaf(xdv[m], xv_, d);
      }
      a = wred(a); d = wred(d);
      if (L == 0) { sh_xpz[t][w] = a + bz; sh_xpdv[t][w] = d + bdv; }
    }
  }

  // ---- persistent register tables (9x8 = 72 floats, as R4) ----
  float wz[8], wdv[8], mw[8], mb[8], al[8], upS[8], loS[8], D[8], tE[8];
  {
    const float s_z = sch[rz], s_dv = sch[rdv], s_r = sch[rr];
#pragma unroll
    for (int m = 0; m < 8; m++) {
      int c = m * 64 + L;
      wz[m]  = s_z  * h2h_v[(size_t)rz  * 512 + c];
      wdv[m] = s_dv * h2h_v[(size_t)rdv * 512 + c];
      mw[m] = modU_w[wrow + c];
      mb[m] = modU_b[wrow + c];
      float alv = alpha[wrow + c];
      al[m] = alv;
      float wrv = s_r * h2h_v[(size_t)rr * 512 + c];
      float t1 = alv / (alv + 1e-5f);   // alpha * (1/(alpha+eps)), prescaled
      upS[m] = fmaxf(1.f - wrv, 0.f) * t1;
      loS[m] = -fmaxf(1.f + wrv, 0.f) * t1;
      float dui = dU0[row + c];
      D[m]  = alv * dui;                // scaled state: D = alpha * dU
      tE[m] = tE0[row + c];
    }
  }
  float v_reg = 0.f, hn_last = 0.f, gb = 0.f;
  if (L == 0) {
    v_reg = v0[b * 512 + i];
    if (w < 4) gb = h2mod_b[w];
  }
  __syncthreads();

  for (int t = 0; t <= 32; t++) {
    const int cur = t & 1, prev = cur ^ 1;
    if (t > 0) {
      const unsigned* eb = exch + ((t - 1) * 8 + b) * 512;
      // ---- arrival: wave 0 polls 32 tag words; sc0 fast path (shared L2,
      // zero fabric traffic), every 8th sample sc1 (IC truth, fallback) ----
      if (w == 0) {
        const unsigned* fp = eb + (L & 31) * 16 + (L & 15);
        unsigned u; int it = 0;
        do {
          u = ((++it) & 7) ? ld_l2(fp) : ld_ic(fp);
        } while (!__all(u >> 31));
      }
      __syncthreads();
      if (tid < 512) {  // one-shot read of h_t; sc0 first, sc1 on retry
        unsigned u = ld_l2(eb + tid);
        int it2 = 0;
        while (!(u >> 31)) u = ((++it2) & 3) ? ld_l2(eb + tid) : ld_ic(eb + tid);
        sh_hbuf[cur][tid] = __uint_as_float(u & 0x7fffffffu);
      }
      __syncthreads();
      // gates: mod = h_t @ h2mod_w.T + b, waves 0..3
      if (w < 4) {
        float p = 0.f;
        const float* mr = sh_mod + w * 512;
#pragma unroll
        for (int m = 0; m < 8; m++) {
          int c = m * 64 + L;
          p = fmaf(sh_hbuf[cur][c], mr[c], p);
        }
        p = wred(p);
        if (L == 0) {
          p += gb;
          sh_gates[w] = (w == 3) ? fmaxf(p, 0.f) : sigm(p);
        }
      }
      __syncthreads();
      // te_n = te + tau_e*(h_{t-1} - te)
      float taue = sh_gates[0];
      if (tid < 512) sh_te[tid] += taue * (sh_hbuf[prev][tid] - sh_te[tid]);
      __syncthreads();
      // tE / D register update (pure VALU, no global loads)
      float tauE = sh_gates[1], tauU = sh_gates[2], mU = sh_gates[3];
      float hn_i = sh_hbuf[cur][i], te_i = sh_te[i];
#pragma unroll
      for (int m = 0; m < 8; m++) {
        int j = m * 64 + L;
        float outer = hn_i * sh_te[j] - te_i * sh_hbuf[cur][j];
        float tEn = tE[m] + tauE * (outer - tE[m]);
        float a = fmaf(mU, mw[m], mb[m]);
        float sshr = (a > 0.5f) ? (a - 0.5f) : ((a < -0.5f) ? (a + 0.5f) : 0.f);
        float Dn = D[m] + tauU * (sshr * (al[m] * tEn) - D[m]);
        D[m] = fminf(fmaxf(Dn, loS[m]), upS[m]);
        tE[m] = tEn;
      }
    }

    if (t < 32) {
      // z/dv dots for step t (x-part precomputed; D = alpha*dU directly)
      float p1 = 0.f, p2 = 0.f;
#pragma unroll
      for (int m = 0; m < 8; m++) {
        int c = m * 64 + L;
        float hc = sh_hbuf[cur][c];
        p1 = fmaf(wz[m], hc, p1);
        p2 = fmaf(wdv[m] + D[m], hc, p2);
      }
      p1 = wred(p1); p2 = wred(p2);
      if (L == 0) {
        float z = sigm(p1 + sh_xpz[t][w]);
        float dv = p2 + sh_xpdv[t][w];
        v_reg += z * (dv - v_reg);
        hn_last = fmaxf(v_reg, 0.f);
        o_outs[(size_t)t * 4096 + b * 512 + i] = hn_last;  // clean copy, fire&forget
        sh_gather[w] = hn_last;                            // LDS gather for exchange
      }
      __syncthreads();  // orders the gather; only plain stores outstanding
      if (w == 15 && L < 16) {
        // ONE 16-lane contiguous 64B tagged store, issued twice:
        // sc1 first (IC coherence point: always-correct slow path), then
        // sc0-only (dirties the SHARED same-XCD L2: the fast path).
        unsigned u = __float_as_uint(sh_gather[L]) | 0x80000000u;
        unsigned* dst = exch + (t * 8 + b) * 512 + q * 16 + L;
        st_ic(dst, u);
        st_l2(dst, u);
      }
    }
  }

  // ---- final writes ----
#pragma unroll
  for (int m = 0; m < 8; m++) {
    int c = m * 64 + L;
    float alv = al[m];
    o_dU[row + c] = (alv != 0.f) ? D[m] * __builtin_amdgcn_rcpf(alv) : 0.f;
    o_tE[row + c] = tE[m];
  }
  if (L == 0) {
    o_v[b * 512 + i] = v_reg;
    o_h[b * 512 + i] = hn_last;
  }
  if (q == 0 && tid < 512) o_te[b * 512 + tid] = sh_te[tid];
}

extern "C" void kernel_launch(void* const* d_in, const int* in_sizes, int n_in,
                              void* d_out, int out_size, void* d_ws, size_t ws_size,
                              hipStream_t stream) {
  const float* x       = (const float*)d_in[0];
  const float* h0      = (const float*)d_in[1];
  const float* v0      = (const float*)d_in[2];
  const float* dU0     = (const float*)d_in[3];
  const float* te0     = (const float*)d_in[4];
  const float* tE0     = (const float*)d_in[5];
  const float* x2h_v   = (const float*)d_in[6];
  const float* x2h_g   = (const float*)d_in[7];
  const float* x2h_b   = (const float*)d_in[8];
  const float* h2h_v   = (const float*)d_in[9];
  const float* h2h_g   = (const float*)d_in[10];
  const float* h2h_b   = (const float*)d_in[11];
  const float* alpha   = (const float*)d_in[12];
  const float* h2mod_w = (const float*)d_in[13];
  const float* h2mod_b = (const float*)d_in[14];
  const float* modU_w  = (const float*)d_in[15];
  const float* modU_b  = (const float*)d_in[16];

  float* out = (float*)d_out;
  // output layout: v(4096) h(4096) dU(2097152) te(4096) tE(2097152) outs(131072)
  float* o_v    = out;
  float* o_h    = out + 4096;
  float* o_dU   = out + 8192;
  float* o_te   = out + 2105344;
  float* o_tE   = out + 2109440;
  float* o_outs = out + 4206592;

  float* wsf = (float*)d_ws;
  float* scx = wsf + 8192;                    // 1536 floats
  float* sch = wsf + 9728;                    // 1536 floats
  unsigned* exch = (unsigned*)d_ws + 12288;   // 32*8*32 lines x 16 words = 512KB

  prenorm_kernel<<<dim3(3072), dim3(64), 0, stream>>>(x2h_v, x2h_g, h2h_v, h2h_g,
                                                      scx, sch, exch);

  persist_kernel<<<dim3(256), dim3(1024), 0, stream>>>(
      x, h0, v0, dU0, te0, tE0, x2h_v, x2h_b, h2h_v, h2h_b, alpha,
      h2mod_w, h2mod_b, modU_w, modU_b, scx, sch, exch,
      o_v, o_h, o_dU, o_te, o_tE, o_outs);
}

// Round 8
// 245.330 us; speedup vs baseline: 1.1763x; 1.0203x over previous
//
#include <hip/hip_runtime.h>
#include <math.h>

// SGRUCell T=32 B=8 I=512 H=512, all f32.
// Persistent kernel: block (q=blk>>3, b=blk&7) owns rows i in [16q,16q+16) of
// batch b; 16 waves, one row per wave. Body = R4 champion (143.5us) except
// the consumer exchange path.
//
// Exchange invariants (paid for in R1/R2/R5/R6/R7 regressions):
//  (1) polled lines are write-once per step and quiesce;
//  (2) no RMW flag lines;
//  (3) EXACTLY ONE spinning wave per block;
//  (4) agent-scope (sc0 sc1) everywhere -- the R7 sc0-only "fast path" is
//      defeated by stale-clean L2 lines (first poll caches the pre-store 0);
//  (5) fused-loop/register restructures of the 5-phase body spill at the
//      128-reg cap (R3/R6 WRITE_SIZE fingerprint) -- body stays verbatim.
//
// R8 delta (consumer only): FUSED poll+read. Wave 0 polls the full 512-word
// exchange block -- 8 contiguous coalesced dword loads per lane in ONE asm
// block with a single vmcnt(0) -- checking EVERY word's sign tag. Per-retry
// fabric cost is 32 line-touches, identical to R4's tag-word poll (which
// also touched all 32 lines); retry frequency is one load-latency period,
// also identical. On detection the data is already in registers -> straight
// to LDS (lane L writes k*64+L: 2 lanes/bank, conflict-free). This deletes
// the separate 512-wide read RTT and one barrier: 5 -> 4 barriers/step.
// Producer: exact R4 -- wave 15 issues ONE 16-lane contiguous 64B store of
// sign-tagged values (hn>=0 => sign bit free) agent-scope.

#define ATOMIC_ST(p, v) __hip_atomic_store((p), (v), __ATOMIC_RELAXED, __HIP_MEMORY_SCOPE_AGENT)

// 8 agent-scope loads at stride 256B + one waitcnt, as a single asm block
// (outputs only defined on block completion => no hoist-past-waitcnt hazard).
__device__ __forceinline__ void ld8_tagged(const unsigned* p, unsigned* u) {
  asm volatile(
      "global_load_dword %0, %8, off sc0 sc1\n\t"
      "global_load_dword %1, %8, off offset:256 sc0 sc1\n\t"
      "global_load_dword %2, %8, off offset:512 sc0 sc1\n\t"
      "global_load_dword %3, %8, off offset:768 sc0 sc1\n\t"
      "global_load_dword %4, %8, off offset:1024 sc0 sc1\n\t"
      "global_load_dword %5, %8, off offset:1280 sc0 sc1\n\t"
      "global_load_dword %6, %8, off offset:1536 sc0 sc1\n\t"
      "global_load_dword %7, %8, off offset:1792 sc0 sc1\n\t"
      "s_waitcnt vmcnt(0)"
      : "=&v"(u[0]), "=&v"(u[1]), "=&v"(u[2]), "=&v"(u[3]),
        "=&v"(u[4]), "=&v"(u[5]), "=&v"(u[6]), "=&v"(u[7])
      : "v"(p)
      : "memory");
}

__device__ __forceinline__ float wred(float v) {
#pragma unroll
  for (int o = 32; o > 0; o >>= 1) v += __shfl_xor(v, o, 64);
  return v;
}
__device__ __forceinline__ float sigm(float x) { return 1.f / (1.f + __expf(-x)); }

__global__ void prenorm_kernel(const float* __restrict__ xv, const float* __restrict__ xg,
                               const float* __restrict__ hv, const float* __restrict__ hg,
                               float* __restrict__ scx, float* __restrict__ sch,
                               unsigned* __restrict__ exch) {
  int r = blockIdx.x, L = threadIdx.x;
  // exch is poisoned 0xAA (sign bit SET = would look ready): clear 131072 words.
  if (r < 2048) exch[r * 64 + L] = 0u;
  const float* vrow; const float* g; float* o; int rr;
  if (r < 1536) { rr = r; vrow = xv + (size_t)r * 512; g = xg; o = scx; }
  else { rr = r - 1536; vrow = hv + (size_t)rr * 512; g = hg; o = sch; }
  float s = 0.f;
#pragma unroll
  for (int m = 0; m < 8; m++) { float v = vrow[m * 64 + L]; s = fmaf(v, v, s); }
  s = wred(s);
  if (L == 0) o[rr] = g[rr] / sqrtf(s);
}

__global__ __launch_bounds__(1024, 4) void persist_kernel(
    const float* __restrict__ x,
    const float* __restrict__ h0, const float* __restrict__ v0,
    const float* __restrict__ dU0, const float* __restrict__ te0,
    const float* __restrict__ tE0,
    const float* __restrict__ x2h_v, const float* __restrict__ x2h_b,
    const float* __restrict__ h2h_v, const float* __restrict__ h2h_b,
    const float* __restrict__ alpha,
    const float* __restrict__ h2mod_w, const float* __restrict__ h2mod_b,
    const float* __restrict__ modU_w, const float* __restrict__ modU_b,
    const float* __restrict__ scx, const float* __restrict__ sch,
    unsigned* __restrict__ exch,
    float* __restrict__ o_v, float* __restrict__ o_h,
    float* __restrict__ o_dU, float* __restrict__ o_te,
    float* __restrict__ o_tE, float* __restrict__ o_outs) {
  __shared__ float sh_hbuf[2][512];   // h ping-pong: buf[t&1] = h_t
  __shared__ float sh_te[512];        // eligibility trace
  __shared__ float sh_mod[2048];      // h2mod_w (4x512)
  __shared__ float sh_xpz[32][16];    // precomputed x-proj (z) + bias, [t][w]
  __shared__ float sh_xpdv[32][16];   // precomputed x-proj (dv) + bias
  __shared__ float sh_gates[4];       // tau_e, tau_E, tau_U, mU
  __shared__ float sh_gather[16];     // per-wave hn gather for the 64B store

  const int tid = threadIdx.x;
  const int w = tid >> 6, L = tid & 63;
  const int b = blockIdx.x & 7, q = blockIdx.x >> 3;
  const int i = q * 16 + w;  // owned row

  // ---- basic LDS staging ----
  if (tid < 512) {
    sh_hbuf[0][tid] = h0[b * 512 + tid];
    sh_te[tid] = te0[b * 512 + tid];
  }
  sh_mod[tid] = h2mod_w[tid];
  sh_mod[tid + 1024] = h2mod_w[tid + 1024];

  const int rz = i, rdv = 1024 + i, rr = 512 + i;
  const size_t row  = ((size_t)(b * 512 + i)) * 512;
  const size_t wrow = (size_t)i * 512;

  // ---- x-projection precompute FIRST (keeps register pressure low) ----
  {
    float xz[8], xdv[8];
    const float sx_z = scx[rz], sx_dv = scx[rdv];
#pragma unroll
    for (int m = 0; m < 8; m++) {
      int c = m * 64 + L;
      xz[m]  = sx_z  * x2h_v[(size_t)rz  * 512 + c];
      xdv[m] = sx_dv * x2h_v[(size_t)rdv * 512 + c];
    }
    float bz = 0.f, bdv = 0.f;
    if (L == 0) {
      bz  = x2h_b[i] + h2h_b[i];
      bdv = x2h_b[1024 + i] + h2h_b[1024 + i];
    }
#pragma unroll 4
    for (int t = 0; t < 32; t++) {
      const float* xr = x + (size_t)t * 4096 + b * 512;
      float a = 0.f, d = 0.f;
#pragma unroll
      for (int m = 0; m < 8; m++) {
        int c = m * 64 + L;
        float xv_ = xr[c];
        a = fmaf(xz[m], xv_, a);
        d = fmaf(xdv[m], xv_, d);
      }
      a = wred(a); d = wred(d);
      if (L == 0) { sh_xpz[t][w] = a + bz; sh_xpdv[t][w] = d + bdv; }
    }
  }

  // ---- persistent register tables (9x8 = 72 floats, as R4) ----
  float wz[8], wdv[8], mw[8], mb[8], al[8], upS[8], loS[8], D[8], tE[8];
  {
    const float s_z = sch[rz], s_dv = sch[rdv], s_r = sch[rr];
#pragma unroll
    for (int m = 0; m < 8; m++) {
      int c = m * 64 + L;
      wz[m]  = s_z  * h2h_v[(size_t)rz  * 512 + c];
      wdv[m] = s_dv * h2h_v[(size_t)rdv * 512 + c];
      mw[m] = modU_w[wrow + c];
      mb[m] = modU_b[wrow + c];
      float alv = alpha[wrow + c];
      al[m] = alv;
      float wrv = s_r * h2h_v[(size_t)rr * 512 + c];
      float t1 = alv / (alv + 1e-5f);   // alpha * (1/(alpha+eps)), prescaled
      upS[m] = fmaxf(1.f - wrv, 0.f) * t1;
      loS[m] = -fmaxf(1.f + wrv, 0.f) * t1;
      float dui = dU0[row + c];
      D[m]  = alv * dui;                // scaled state: D = alpha * dU
      tE[m] = tE0[row + c];
    }
  }
  float v_reg = 0.f, hn_last = 0.f, gb = 0.f;
  if (L == 0) {
    v_reg = v0[b * 512 + i];
    if (w < 4) gb = h2mod_b[w];
  }
  __syncthreads();

  for (int t = 0; t <= 32; t++) {
    const int cur = t & 1, prev = cur ^ 1;
    if (t > 0) {
      const unsigned* eb = exch + ((t - 1) * 8 + b) * 512;
      // ---- fused poll+read: wave 0 polls ALL 512 words (8 coalesced loads
      // per lane, one vmcnt, every tag checked); data lands in registers at
      // the moment of detection -> straight to LDS. One RTT, one barrier. ----
      if (w == 0) {
        unsigned u[8];
        for (;;) {
          ld8_tagged(eb + L, u);
          unsigned acc = u[0] & u[1] & u[2] & u[3] & u[4] & u[5] & u[6] & u[7];
          if (__all(acc >> 31)) break;
        }
#pragma unroll
        for (int k = 0; k < 8; k++)
          sh_hbuf[cur][k * 64 + L] = __uint_as_float(u[k] & 0x7fffffffu);
      }
      __syncthreads();  // b1: sh_hbuf[cur] = h_t complete
      // gates: mod = h_t @ h2mod_w.T + b, waves 0..3
      if (w < 4) {
        float p = 0.f;
        const float* mr = sh_mod + w * 512;
#pragma unroll
        for (int m = 0; m < 8; m++) {
          int c = m * 64 + L;
          p = fmaf(sh_hbuf[cur][c], mr[c], p);
        }
        p = wred(p);
        if (L == 0) {
          p += gb;
          sh_gates[w] = (w == 3) ? fmaxf(p, 0.f) : sigm(p);
        }
      }
      __syncthreads();  // b2: gates ready
      // te_n = te + tau_e*(h_{t-1} - te)
      float taue = sh_gates[0];
      if (tid < 512) sh_te[tid] += taue * (sh_hbuf[prev][tid] - sh_te[tid]);
      __syncthreads();  // b3: te ready
      // tE / D register update (pure VALU, no global loads)
      float tauE = sh_gates[1], tauU = sh_gates[2], mU = sh_gates[3];
      float hn_i = sh_hbuf[cur][i], te_i = sh_te[i];
#pragma unroll
      for (int m = 0; m < 8; m++) {
        int j = m * 64 + L;
        float outer = hn_i * sh_te[j] - te_i * sh_hbuf[cur][j];
        float tEn = tE[m] + tauE * (outer - tE[m]);
        float a = fmaf(mU, mw[m], mb[m]);
        float sshr = (a > 0.5f) ? (a - 0.5f) : ((a < -0.5f) ? (a + 0.5f) : 0.f);
        float Dn = D[m] + tauU * (sshr * (al[m] * tEn) - D[m]);
        D[m] = fminf(fmaxf(Dn, loS[m]), upS[m]);
        tE[m] = tEn;
      }
    }

    if (t < 32) {
      // z/dv dots for step t (x-part precomputed; D = alpha*dU directly)
      float p1 = 0.f, p2 = 0.f;
#pragma unroll
      for (int m = 0; m < 8; m++) {
        int c = m * 64 + L;
        float hc = sh_hbuf[cur][c];
        p1 = fmaf(wz[m], hc, p1);
        p2 = fmaf(wdv[m] + D[m], hc, p2);
      }
      p1 = wred(p1); p2 = wred(p2);
      if (L == 0) {
        float z = sigm(p1 + sh_xpz[t][w]);
        float dv = p2 + sh_xpdv[t][w];
        v_reg += z * (dv - v_reg);
        hn_last = fmaxf(v_reg, 0.f);
        o_outs[(size_t)t * 4096 + b * 512 + i] = hn_last;  // clean copy, fire&forget
        sh_gather[w] = hn_last;                            // LDS gather for exchange
      }
      __syncthreads();  // b4: orders the gather; only plain stores outstanding
      if (w == 15 && L < 16) {
        // ONE 16-lane contiguous 64B tagged store: data is its own flag.
        unsigned u = __float_as_uint(sh_gather[L]) | 0x80000000u;
        ATOMIC_ST(exch + (t * 8 + b) * 512 + q * 16 + L, u);
      }
    }
  }

  // ---- final writes ----
#pragma unroll
  for (int m = 0; m < 8; m++) {
    int c = m * 64 + L;
    float alv = al[m];
    o_dU[row + c] = (alv != 0.f) ? D[m] * __builtin_amdgcn_rcpf(alv) : 0.f;
    o_tE[row + c] = tE[m];
  }
  if (L == 0) {
    o_v[b * 512 + i] = v_reg;
    o_h[b * 512 + i] = hn_last;
  }
  if (q == 0 && tid < 512) o_te[b * 512 + tid] = sh_te[tid];
}

extern "C" void kernel_launch(void* const* d_in, const int* in_sizes, int n_in,
                              void* d_out, int out_size, void* d_ws, size_t ws_size,
                              hipStream_t stream) {
  const float* x       = (const float*)d_in[0];
  const float* h0      = (const float*)d_in[1];
  const float* v0      = (const float*)d_in[2];
  const float* dU0     = (const float*)d_in[3];
  const float* te0     = (const float*)d_in[4];
  const float* tE0     = (const float*)d_in[5];
  const float* x2h_v   = (const float*)d_in[6];
  const float* x2h_g   = (const float*)d_in[7];
  const float* x2h_b   = (const float*)d_in[8];
  const float* h2h_v   = (const float*)d_in[9];
  const float* h2h_g   = (const float*)d_in[10];
  const float* h2h_b   = (const float*)d_in[11];
  const float* alpha   = (const float*)d_in[12];
  const float* h2mod_w = (const float*)d_in[13];
  const float* h2mod_b = (const float*)d_in[14];
  const float* modU_w  = (const float*)d_in[15];
  const float* modU_b  = (const float*)d_in[16];

  float* out = (float*)d_out;
  // output layout: v(4096) h(4096) dU(2097152) te(4096) tE(2097152) outs(131072)
  float* o_v    = out;
  float* o_h    = out + 4096;
  float* o_dU   = out + 8192;
  float* o_te   = out + 2105344;
  float* o_tE   = out + 2109440;
  float* o_outs = out + 4206592;

  float* wsf = (float*)d_ws;
  float* scx = wsf + 8192;                    // 1536 floats
  float* sch = wsf + 9728;                    // 1536 floats
  unsigned* exch = (unsigned*)d_ws + 12288;   // 32*8*32 lines x 16 words = 512KB

  prenorm_kernel<<<dim3(3072), dim3(64), 0, stream>>>(x2h_v, x2h_g, h2h_v, h2h_g,
                                                      scx, sch, exch);

  persist_kernel<<<dim3(256), dim3(1024), 0, stream>>>(
      x, h0, v0, dU0, te0, tE0, x2h_v, x2h_b, h2h_v, h2h_b, alpha,
      h2mod_w, h2mod_b, modU_w, modU_b, scx, sch, exch,
      o_v, o_h, o_dU, o_te, o_tE, o_outs);
}